// Round 10
// baseline (2870.066 us; speedup 1.0000x reference)
//
#include <hip/hip_runtime.h>
#include <hip/hip_bf16.h>

// ---------------------------------------------------------------------------
// Fully fake-quantized Llama MLP on MI355X (gfx950).
// Device inputs: float32. Device output: float32.
// Intermediates bf16; GEMMs via bf16 MFMA 16x16x32, f32 accumulate.
// R10: streaming kernels = block-chunked MLP (8 loads in flight) WITH
//      lane-contiguous coalescing (lane addr = blockbase + c*chunk + tid*16B).
//      R9 lesson: per-lane-contiguous spans (tid*32) break instruction-level
//      coalescing -> 4x transactions -> epass2 at 522us. Both properties at
//      once via block-level chunk striding.
//      GEMM unchanged (proven 510us, (256,4); (256,5) spills — see R7).
// ---------------------------------------------------------------------------

typedef __bf16 bf16x8 __attribute__((ext_vector_type(8)));
typedef float f32x4 __attribute__((ext_vector_type(4)));
typedef unsigned short ushort8 __attribute__((ext_vector_type(8)));
typedef unsigned short ushort4v __attribute__((ext_vector_type(4)));
typedef unsigned short u16;

#define SLOT_X 0
#define SLOT_UP 1
#define SLOT_GATE 2
#define SLOT_G2 3
#define SLOT_O 4

__device__ __forceinline__ float bf2f(u16 u) {
    return __uint_as_float(((unsigned)u) << 16);
}
__device__ __forceinline__ u16 f2bf(float f) {
    unsigned x = __float_as_uint(f);
    unsigned r = (x + 0x7FFFu + ((x >> 16) & 1u)) >> 16;  // RNE
    return (u16)r;
}

__device__ __forceinline__ unsigned encf(float f) {
    unsigned u = __float_as_uint(f);
    return (u & 0x80000000u) ? ~u : (u | 0x80000000u);
}
__device__ __forceinline__ float decf(unsigned s) {
    unsigned u = (s & 0x80000000u) ? (s ^ 0x80000000u) : ~s;
    return __uint_as_float(u);
}

__device__ __forceinline__ void wave_minmax_atomic(float mn, float mx, unsigned* slots, int sidx) {
    for (int off = 32; off; off >>= 1) {
        mn = fminf(mn, __shfl_xor(mn, off));
        mx = fmaxf(mx, __shfl_xor(mx, off));
    }
    if ((threadIdx.x & 63) == 0) {
        atomicMin(&slots[sidx * 2 + 0], encf(mn));
        atomicMax(&slots[sidx * 2 + 1], encf(mx));
    }
}

__device__ __forceinline__ void get_scale_zp(const unsigned* slots, int sidx, float& scale, float& zp) {
    float mn = decf(slots[sidx * 2 + 0]);
    float mx = decf(slots[sidx * 2 + 1]);
    scale = fmaxf((mx - mn) / 65535.0f, 1e-12f);
    zp = fminf(fmaxf(rintf(-mn / scale), 0.0f), 65535.0f);
}

__device__ __forceinline__ float qdq_act(float x, float scale, float zp) {
    float q = rintf(x / scale) + zp;
    q = fminf(fmaxf(q, 0.0f), 65535.0f);
    return (q - zp) * scale;
}

__device__ __forceinline__ void load_lds16(const void* g, void* l) {
    __builtin_amdgcn_global_load_lds((const __attribute__((address_space(1))) void*)g,
                                     (__attribute__((address_space(3))) void*)l, 16, 0, 0);
}

// ---------------------------------------------------------------------------
__global__ void init_slots(unsigned* slots) {
    if (threadIdx.x < 16) slots[threadIdx.x] = 0x80000000u;  // enc(0.0f)
}

// Block covers 8192 contiguous floats; lane loads 8 float4 chunks, coalesced.
// Grid*8192 == n exactly.
__global__ __launch_bounds__(256) void minmax_x(const float* __restrict__ in, long n,
                                                unsigned* slots, int sidx) {
    long base = (long)blockIdx.x * 8192 + threadIdx.x * 4;
    float4 v[8];
    #pragma unroll
    for (int c = 0; c < 8; ++c) v[c] = *(const float4*)(in + base + c * 1024);
    float mn = 0.f, mx = 0.f;
    #pragma unroll
    for (int c = 0; c < 8; ++c) {
        mn = fminf(fminf(mn, fminf(v[c].x, v[c].y)), fminf(v[c].z, v[c].w));
        mx = fmaxf(fmaxf(mx, fmaxf(v[c].x, v[c].y)), fmaxf(v[c].z, v[c].w));
    }
    wave_minmax_atomic(mn, mx, slots, sidx);
}

// x (f32) -> qdq -> bf16. Same addressing as minmax_x; 8B stores coalesced.
__global__ __launch_bounds__(256) void qdq_x_kernel(const float* __restrict__ in, u16* __restrict__ out,
                                                    long n, const unsigned* slots, int sidx) {
    float scale, zp;
    get_scale_zp(slots, sidx, scale, zp);
    long base = (long)blockIdx.x * 8192 + threadIdx.x * 4;
    float4 v[8];
    #pragma unroll
    for (int c = 0; c < 8; ++c) v[c] = *(const float4*)(in + base + c * 1024);
    #pragma unroll
    for (int c = 0; c < 8; ++c) {
        ushort4v o;
        o[0] = f2bf(qdq_act(v[c].x, scale, zp));
        o[1] = f2bf(qdq_act(v[c].y, scale, zp));
        o[2] = f2bf(qdq_act(v[c].z, scale, zp));
        o[3] = f2bf(qdq_act(v[c].w, scale, zp));
        *(ushort4v*)(out + base + c * 1024) = o;
    }
}

// per-(row, 32-block) symmetric 4-bit weight fake-quant; f32 -> bf16.
// Block covers 8192 contiguous floats. Lane loads 8 float4 (one per
// 1024-float chunk) — coalesced, 8 in flight. Each 32-float quant block is
// one aligned 8-lane group at one chunk: __shfl_xor 1,2,4 reduction.
// Grid*8192 == 32*nblk exactly.
__device__ __forceinline__ void quant_w_body(const float* __restrict__ W, u16* __restrict__ Wq) {
    long base = (long)blockIdx.x * 8192 + threadIdx.x * 4;
    float4 v[8];
    #pragma unroll
    for (int c = 0; c < 8; ++c) v[c] = *(const float4*)(W + base + c * 1024);
    #pragma unroll
    for (int c = 0; c < 8; ++c) {
        float am = fmaxf(fmaxf(fabsf(v[c].x), fabsf(v[c].y)), fmaxf(fabsf(v[c].z), fabsf(v[c].w)));
        am = fmaxf(am, __shfl_xor(am, 1));
        am = fmaxf(am, __shfl_xor(am, 2));
        am = fmaxf(am, __shfl_xor(am, 4));
        float scale = fmaxf(am / 7.0f, 1e-12f);
        float inv = 1.0f / scale;
        ushort4v o;
        float q0 = fminf(fmaxf(rintf(v[c].x * inv), -8.0f), 7.0f);
        float q1 = fminf(fmaxf(rintf(v[c].y * inv), -8.0f), 7.0f);
        float q2 = fminf(fmaxf(rintf(v[c].z * inv), -8.0f), 7.0f);
        float q3 = fminf(fmaxf(rintf(v[c].w * inv), -8.0f), 7.0f);
        o[0] = f2bf(q0 * scale);
        o[1] = f2bf(q1 * scale);
        o[2] = f2bf(q2 * scale);
        o[3] = f2bf(q3 * scale);
        *(ushort4v*)(Wq + base + c * 1024) = o;
    }
}
__global__ __launch_bounds__(256) void quant_w_up(const float* W, u16* Wq)   { quant_w_body(W, Wq); }
__global__ __launch_bounds__(256) void quant_w_gate(const float* W, u16* Wq) { quant_w_body(W, Wq); }
__global__ __launch_bounds__(256) void quant_w_down(const float* W, u16* Wq) { quant_w_body(W, Wq); }

// elementwise chain: g1=qdq(gate); sig=fixed_qdq(sigmoid(g1)); g2=g1*sig;
// STAGE1: minmax(g2) -> SLOT_G2
// STAGE2: o = qdq(g2)*qdq(up); minmax(o) -> SLOT_O
// STAGE3: out = bf16(qdq(o))   (out aliases gate; same-index RAW per thread)
// Block covers 8192 contiguous bf16; lane loads 4 ushort8 per operand at
// base + c*2048 — coalesced, 4-8 in flight. Grid*8192 == n exactly.
template <int STAGEI>
__device__ __forceinline__ void epass_body(const u16* gate, const u16* up, u16* out,
                                           unsigned* slots) {
    float g_s, g_z, u_s = 1.f, u_z = 0.f, g2_s = 1.f, g2_z = 0.f, o_s = 1.f, o_z = 0.f;
    get_scale_zp(slots, SLOT_GATE, g_s, g_z);
    if (STAGEI >= 2) {
        get_scale_zp(slots, SLOT_UP, u_s, u_z);
        get_scale_zp(slots, SLOT_G2, g2_s, g2_z);
    }
    if (STAGEI >= 3) get_scale_zp(slots, SLOT_O, o_s, o_z);

    long base = (long)blockIdx.x * 8192 + threadIdx.x * 8;
    ushort8 gv[4], uv[4];
    #pragma unroll
    for (int c = 0; c < 4; ++c) gv[c] = *(const ushort8*)(gate + base + c * 2048);
    if (STAGEI >= 2) {
        #pragma unroll
        for (int c = 0; c < 4; ++c) uv[c] = *(const ushort8*)(up + base + c * 2048);
    }

    float mn = 0.f, mx = 0.f;
    #pragma unroll
    for (int c = 0; c < 4; ++c) {
        ushort8 ov;
        #pragma unroll
        for (int j = 0; j < 8; ++j) {
            float g1 = qdq_act(bf2f(gv[c][j]), g_s, g_z);
            float s = 1.0f / (1.0f + __expf(-g1));
            float sq = fminf(fmaxf(rintf(s * 65536.0f), 0.0f), 65535.0f) * (1.0f / 65536.0f);
            float g2 = g1 * sq;
            if (STAGEI == 1) {
                mn = fminf(mn, g2);
                mx = fmaxf(mx, g2);
            } else {
                float g2q = qdq_act(g2, g2_s, g2_z);
                float u1 = qdq_act(bf2f(uv[c][j]), u_s, u_z);
                float o = g2q * u1;
                if (STAGEI == 2) {
                    mn = fminf(mn, o);
                    mx = fmaxf(mx, o);
                } else {
                    ov[j] = f2bf(qdq_act(o, o_s, o_z));
                }
            }
        }
        if (STAGEI == 3) *(ushort8*)(out + base + c * 2048) = ov;
    }
    if (STAGEI == 1) wave_minmax_atomic(mn, mx, slots, SLOT_G2);
    if (STAGEI == 2) wave_minmax_atomic(mn, mx, slots, SLOT_O);
}
__global__ __launch_bounds__(256) void epass1(const u16* g, const u16* u, u16* o, unsigned* s) { epass_body<1>(g, u, o, s); }
__global__ __launch_bounds__(256) void epass2(const u16* g, const u16* u, u16* o, unsigned* s) { epass_body<2>(g, u, o, s); }
__global__ __launch_bounds__(256) void epass3(const u16* g, const u16* u, u16* o, unsigned* s) { epass_body<3>(g, u, o, s); }

// ---------------------------------------------------------------------------
// C = A @ B^T : A [M,K] bf16 row-major, B [N,K] bf16 row-major.
// C is bf16 (u16) or f32 per OutT. 128x128 tile, BK=64, 4 waves (2x2),
// each wave 64x64 via 4x4 mfma_16x16x32. Optionally fuses global min/max.
// Grid: 1D supertiled (SUPER_M=16, bm-inner) -> working set L3-resident.
// __launch_bounds__(256,4): 4 blocks/CU. DO NOT raise to 5: wave needs
// 60 VGPR + 64 acc = 124 unified regs > 512/5 budget -> acc spills to
// scratch (measured R7: WRITE_SIZE 89 MB -> 2.7 GB, 510 -> 1190 us).
template <bool MINMAX, typename OutT>
__device__ __forceinline__ void gemm_body(const u16* __restrict__ A, const u16* __restrict__ B,
                                          OutT* __restrict__ C, int M, int N, int K,
                                          unsigned* slots, int sidx) {
    __shared__ u16 Als[128 * 64];
    __shared__ u16 Bls[128 * 64];
    const int wave = threadIdx.x >> 6;
    const int lane = threadIdx.x & 63;
    const int wr = wave >> 1, wc = wave & 1;
    const int l15 = lane & 15, lhi = lane >> 4;

    // supertile mapping: stripes of 16 bm; within a stripe bm varies fastest
    const int ntn = N >> 7;
    const int rowspan = 16 * ntn;
    const int stripe = blockIdx.x / rowspan;
    const int rem = blockIdx.x - stripe * rowspan;
    const int bn = rem >> 4;
    const int bm = (stripe << 4) + (rem & 15);

    f32x4 acc[4][4] = {};

    const u16* Abase = A + (size_t)bm * 128 * K;
    const u16* Bbase = B + (size_t)bn * 128 * K;

    for (int k0 = 0; k0 < K; k0 += 64) {
        #pragma unroll
        for (int i = 0; i < 4; ++i) {
            int c = i * 4 + wave;            // 16 chunks of 512 elems (1KB/wave-inst)
            int e = c * 512 + lane * 8;
            int row = e >> 6, col = e & 63;
            load_lds16(Abase + (size_t)row * K + k0 + col, &Als[c * 512]);
        }
        #pragma unroll
        for (int i = 0; i < 4; ++i) {
            int c = i * 4 + wave;
            int e = c * 512 + lane * 8;
            int row = e >> 6, col = e & 63;
            load_lds16(Bbase + (size_t)row * K + k0 + col, &Bls[c * 512]);
        }
        __syncthreads();
        #pragma unroll
        for (int kk = 0; kk < 64; kk += 32) {
            bf16x8 af[4], bfr[4];
            #pragma unroll
            for (int m = 0; m < 4; ++m)
                af[m] = *(const bf16x8*)&Als[(wr * 64 + m * 16 + l15) * 64 + kk + lhi * 8];
            #pragma unroll
            for (int n = 0; n < 4; ++n)
                bfr[n] = *(const bf16x8*)&Bls[(wc * 64 + n * 16 + l15) * 64 + kk + lhi * 8];
            #pragma unroll
            for (int m = 0; m < 4; ++m)
                #pragma unroll
                for (int n = 0; n < 4; ++n)
                    acc[m][n] = __builtin_amdgcn_mfma_f32_16x16x32_bf16(af[m], bfr[n], acc[m][n], 0, 0, 0);
        }
        __syncthreads();
    }

    float mn = 0.f, mx = 0.f;
    #pragma unroll
    for (int m = 0; m < 4; ++m) {
        #pragma unroll
        for (int n = 0; n < 4; ++n) {
            int col = bn * 128 + wc * 64 + n * 16 + l15;
            int row0 = bm * 128 + wr * 64 + m * 16 + lhi * 4;
            #pragma unroll
            for (int j = 0; j < 4; ++j) {
                float f = acc[m][n][j];
                if (sizeof(OutT) == 2) {
                    u16 h = f2bf(f);
                    ((u16*)C)[(size_t)(row0 + j) * N + col] = h;
                    if (MINMAX) {
                        float g = bf2f(h);
                        mn = fminf(mn, g);
                        mx = fmaxf(mx, g);
                    }
                } else {
                    ((float*)C)[(size_t)(row0 + j) * N + col] = f;
                    if (MINMAX) {
                        mn = fminf(mn, f);
                        mx = fmaxf(mx, f);
                    }
                }
            }
        }
    }
    if (MINMAX) wave_minmax_atomic(mn, mx, slots, sidx);
}

__global__ __launch_bounds__(256, 4) void gemm_up(const u16* A, const u16* B, u16* C,
                                                  int M, int N, int K, unsigned* slots, int sidx) {
    gemm_body<true, u16>(A, B, C, M, N, K, slots, sidx);
}
__global__ __launch_bounds__(256, 4) void gemm_gate(const u16* A, const u16* B, u16* C,
                                                    int M, int N, int K, unsigned* slots, int sidx) {
    gemm_body<true, u16>(A, B, C, M, N, K, slots, sidx);
}
__global__ __launch_bounds__(256, 4) void gemm_down(const u16* A, const u16* B, float* C,
                                                    int M, int N, int K, unsigned* slots, int sidx) {
    gemm_body<false, float>(A, B, C, M, N, K, slots, sidx);
}

// ---------------------------------------------------------------------------
extern "C" void kernel_launch(void* const* d_in, const int* in_sizes, int n_in,
                              void* d_out, int out_size, void* d_ws, size_t ws_size,
                              hipStream_t stream) {
    const float* x  = (const float*)d_in[0];   // [2,2048,4096] f32
    const float* wg = (const float*)d_in[1];   // [11008,4096] f32
    const float* wu = (const float*)d_in[2];   // [11008,4096] f32
    const float* wd = (const float*)d_in[3];   // [4096,11008] f32
    float* out = (float*)d_out;                // [2,2048,4096] f32

    const int M = 4096, H = 4096, I = 11008;
    const long NX = (long)M * H;               // 16,777,216 = 2048*8192
    const long NW = (long)I * H;               // 45,088,768 = 5504*8192

    char* ws = (char*)d_ws;
    unsigned* slots = (unsigned*)ws;
    u16* xq    = (u16*)(ws + 256);
    u16* wqs   = (u16*)(ws + 256 + 33554432UL);
    u16* upb   = (u16*)(ws + 256 + 33554432UL + 90177536UL);
    u16* gateb = (u16*)(ws + 256 + 33554432UL + 2 * 90177536UL);

    init_slots<<<1, 64, 0, stream>>>(slots);
    minmax_x<<<2048, 256, 0, stream>>>(x, NX, slots, SLOT_X);
    qdq_x_kernel<<<2048, 256, 0, stream>>>(x, xq, NX, slots, SLOT_X);

    const int nwg_ug = (M / 128) * (I / 128);   // 32*86 = 2752
    const int nwg_d  = (M / 128) * (H / 128);   // 32*32 = 1024

    quant_w_up<<<5504, 256, 0, stream>>>(wu, wqs);
    gemm_up<<<nwg_ug, 256, 0, stream>>>(xq, wqs, upb, M, I, H, slots, SLOT_UP);

    quant_w_gate<<<5504, 256, 0, stream>>>(wg, wqs);
    gemm_gate<<<nwg_ug, 256, 0, stream>>>(xq, wqs, gateb, M, I, H, slots, SLOT_GATE);

    epass1<<<5504, 256, 0, stream>>>(gateb, nullptr, nullptr, slots);
    epass2<<<5504, 256, 0, stream>>>(gateb, upb, nullptr, slots);
    epass3<<<5504, 256, 0, stream>>>(gateb, upb, gateb, slots);

    quant_w_down<<<5504, 256, 0, stream>>>(wd, wqs);
    gemm_down<<<nwg_d, 256, 0, stream>>>(gateb, wqs, out, M, H, I, nullptr, 0);
}

// Round 11
// 2811.128 us; speedup vs baseline: 1.0210x; 1.0210x over previous
//
#include <hip/hip_runtime.h>
#include <hip/hip_bf16.h>

// ---------------------------------------------------------------------------
// Fully fake-quantized Llama MLP on MI355X (gfx950).
// Device inputs: float32. Device output: float32.
// Intermediates bf16; GEMMs via bf16 MFMA 16x16x32, f32 accumulate.
// R11: epass rebuilt — grid-stride 4x8 iters with 2-deep prefetch, and all
//      per-element f32 divisions replaced by inv-scale multiplies + rcp
//      (R10 evidence: epass ~1290us total, stall-bound on div/exp chains;
//      VALUBusy 18%, coalesced, 177 GB/s — not memory, not issue).
//      quant_w/minmax/qdq_x keep R10's coalesced single-shot form (fast).
//      GEMM unchanged (proven 510us, (256,4); (256,5) spills — see R7).
// ---------------------------------------------------------------------------

typedef __bf16 bf16x8 __attribute__((ext_vector_type(8)));
typedef float f32x4 __attribute__((ext_vector_type(4)));
typedef unsigned short ushort8 __attribute__((ext_vector_type(8)));
typedef unsigned short ushort4v __attribute__((ext_vector_type(4)));
typedef unsigned short u16;

#define SLOT_X 0
#define SLOT_UP 1
#define SLOT_GATE 2
#define SLOT_G2 3
#define SLOT_O 4

__device__ __forceinline__ float bf2f(u16 u) {
    return __uint_as_float(((unsigned)u) << 16);
}
__device__ __forceinline__ u16 f2bf(float f) {
    unsigned x = __float_as_uint(f);
    unsigned r = (x + 0x7FFFu + ((x >> 16) & 1u)) >> 16;  // RNE
    return (u16)r;
}

__device__ __forceinline__ unsigned encf(float f) {
    unsigned u = __float_as_uint(f);
    return (u & 0x80000000u) ? ~u : (u | 0x80000000u);
}
__device__ __forceinline__ float decf(unsigned s) {
    unsigned u = (s & 0x80000000u) ? (s ^ 0x80000000u) : ~s;
    return __uint_as_float(u);
}

__device__ __forceinline__ void wave_minmax_atomic(float mn, float mx, unsigned* slots, int sidx) {
    for (int off = 32; off; off >>= 1) {
        mn = fminf(mn, __shfl_xor(mn, off));
        mx = fmaxf(mx, __shfl_xor(mx, off));
    }
    if ((threadIdx.x & 63) == 0) {
        atomicMin(&slots[sidx * 2 + 0], encf(mn));
        atomicMax(&slots[sidx * 2 + 1], encf(mx));
    }
}

__device__ __forceinline__ void get_scale_zp(const unsigned* slots, int sidx, float& scale, float& zp) {
    float mn = decf(slots[sidx * 2 + 0]);
    float mx = decf(slots[sidx * 2 + 1]);
    scale = fmaxf((mx - mn) / 65535.0f, 1e-12f);
    zp = fminf(fmaxf(rintf(-mn / scale), 0.0f), 65535.0f);
}

// qdq with precomputed inverse scale (no per-element division)
__device__ __forceinline__ float qdq_i(float x, float scale, float inv, float zp) {
    float q = rintf(x * inv) + zp;
    q = fminf(fmaxf(q, 0.0f), 65535.0f);
    return (q - zp) * scale;
}

__device__ __forceinline__ void load_lds16(const void* g, void* l) {
    __builtin_amdgcn_global_load_lds((const __attribute__((address_space(1))) void*)g,
                                     (__attribute__((address_space(3))) void*)l, 16, 0, 0);
}

// ---------------------------------------------------------------------------
__global__ void init_slots(unsigned* slots) {
    if (threadIdx.x < 16) slots[threadIdx.x] = 0x80000000u;  // enc(0.0f)
}

// Block covers 8192 contiguous floats; lane loads 8 float4 chunks, coalesced.
__global__ __launch_bounds__(256) void minmax_x(const float* __restrict__ in, long n,
                                                unsigned* slots, int sidx) {
    long base = (long)blockIdx.x * 8192 + threadIdx.x * 4;
    float4 v[8];
    #pragma unroll
    for (int c = 0; c < 8; ++c) v[c] = *(const float4*)(in + base + c * 1024);
    float mn = 0.f, mx = 0.f;
    #pragma unroll
    for (int c = 0; c < 8; ++c) {
        mn = fminf(fminf(mn, fminf(v[c].x, v[c].y)), fminf(v[c].z, v[c].w));
        mx = fmaxf(fmaxf(mx, fmaxf(v[c].x, v[c].y)), fmaxf(v[c].z, v[c].w));
    }
    wave_minmax_atomic(mn, mx, slots, sidx);
}

// x (f32) -> qdq -> bf16. inv-scale multiplies.
__global__ __launch_bounds__(256) void qdq_x_kernel(const float* __restrict__ in, u16* __restrict__ out,
                                                    long n, const unsigned* slots, int sidx) {
    float scale, zp;
    get_scale_zp(slots, sidx, scale, zp);
    float inv = 1.0f / scale;
    long base = (long)blockIdx.x * 8192 + threadIdx.x * 4;
    float4 v[8];
    #pragma unroll
    for (int c = 0; c < 8; ++c) v[c] = *(const float4*)(in + base + c * 1024);
    #pragma unroll
    for (int c = 0; c < 8; ++c) {
        ushort4v o;
        o[0] = f2bf(qdq_i(v[c].x, scale, inv, zp));
        o[1] = f2bf(qdq_i(v[c].y, scale, inv, zp));
        o[2] = f2bf(qdq_i(v[c].z, scale, inv, zp));
        o[3] = f2bf(qdq_i(v[c].w, scale, inv, zp));
        *(ushort4v*)(out + base + c * 1024) = o;
    }
}

// per-(row, 32-block) symmetric 4-bit weight fake-quant; f32 -> bf16.
// Lane loads 8 float4 (one per 1024-float chunk) — coalesced, 8 in flight.
// Each 32-float quant block = one aligned 8-lane group: shfl_xor 1,2,4.
__device__ __forceinline__ void quant_w_body(const float* __restrict__ W, u16* __restrict__ Wq) {
    long base = (long)blockIdx.x * 8192 + threadIdx.x * 4;
    float4 v[8];
    #pragma unroll
    for (int c = 0; c < 8; ++c) v[c] = *(const float4*)(W + base + c * 1024);
    #pragma unroll
    for (int c = 0; c < 8; ++c) {
        float am = fmaxf(fmaxf(fabsf(v[c].x), fabsf(v[c].y)), fmaxf(fabsf(v[c].z), fabsf(v[c].w)));
        am = fmaxf(am, __shfl_xor(am, 1));
        am = fmaxf(am, __shfl_xor(am, 2));
        am = fmaxf(am, __shfl_xor(am, 4));
        float scale = fmaxf(am / 7.0f, 1e-12f);
        float inv = 1.0f / scale;
        ushort4v o;
        float q0 = fminf(fmaxf(rintf(v[c].x * inv), -8.0f), 7.0f);
        float q1 = fminf(fmaxf(rintf(v[c].y * inv), -8.0f), 7.0f);
        float q2 = fminf(fmaxf(rintf(v[c].z * inv), -8.0f), 7.0f);
        float q3 = fminf(fmaxf(rintf(v[c].w * inv), -8.0f), 7.0f);
        o[0] = f2bf(q0 * scale);
        o[1] = f2bf(q1 * scale);
        o[2] = f2bf(q2 * scale);
        o[3] = f2bf(q3 * scale);
        *(ushort4v*)(Wq + base + c * 1024) = o;
    }
}
__global__ __launch_bounds__(256) void quant_w_up(const float* W, u16* Wq)   { quant_w_body(W, Wq); }
__global__ __launch_bounds__(256) void quant_w_gate(const float* W, u16* Wq) { quant_w_body(W, Wq); }
__global__ __launch_bounds__(256) void quant_w_down(const float* W, u16* Wq) { quant_w_body(W, Wq); }

// elementwise chain: g1=qdq(gate); sig=fixed_qdq(sigmoid(g1)); g2=g1*sig;
// STAGE1: minmax(g2) -> SLOT_G2
// STAGE2: o = qdq(g2)*qdq(up); minmax(o) -> SLOT_O
// STAGE3: out = bf16(qdq(o))  (out aliases gate; partitions disjoint -> safe)
// Grid-stride, exactly 4 iterations of 8 elems/lane (5504*256*8*4 == NW),
// 2-deep prefetch (load it+1 before processing it). No per-element division:
// inv-scale multiplies + rcp for sigmoid denominator.
template <int STAGEI>
__device__ __forceinline__ void epass_body(const u16* __restrict__ gate, const u16* __restrict__ up,
                                           u16* __restrict__ out, unsigned* slots) {
    float g_s, g_z;
    get_scale_zp(slots, SLOT_GATE, g_s, g_z);
    float g_i = 1.0f / g_s;
    float u_s = 1.f, u_z = 0.f, u_i = 1.f, g2_s = 1.f, g2_z = 0.f, g2_i = 1.f;
    float o_s = 1.f, o_z = 0.f, o_i = 1.f;
    if (STAGEI >= 2) {
        get_scale_zp(slots, SLOT_UP, u_s, u_z);   u_i = 1.0f / u_s;
        get_scale_zp(slots, SLOT_G2, g2_s, g2_z); g2_i = 1.0f / g2_s;
    }
    if (STAGEI >= 3) {
        get_scale_zp(slots, SLOT_O, o_s, o_z);    o_i = 1.0f / o_s;
    }

    const long stride = (long)gridDim.x * blockDim.x * 8;   // 11,272,192
    long i = ((long)blockIdx.x * blockDim.x + threadIdx.x) * 8;

    ushort8 gv = *(const ushort8*)(gate + i);
    ushort8 uv = {};
    if (STAGEI >= 2) uv = *(const ushort8*)(up + i);

    float mn = 0.f, mx = 0.f;
    #pragma unroll
    for (int it = 0; it < 4; ++it) {
        ushort8 gv2 = {}, uv2 = {};
        if (it < 3) {
            gv2 = *(const ushort8*)(gate + i + stride);
            if (STAGEI >= 2) uv2 = *(const ushort8*)(up + i + stride);
        }
        ushort8 ov;
        #pragma unroll
        for (int j = 0; j < 8; ++j) {
            float g1 = qdq_i(bf2f(gv[j]), g_s, g_i, g_z);
            float e = __expf(-g1);
            float s = __builtin_amdgcn_rcpf(1.0f + e);
            float sq = fminf(fmaxf(rintf(s * 65536.0f), 0.0f), 65535.0f) * (1.0f / 65536.0f);
            float g2 = g1 * sq;
            if (STAGEI == 1) {
                mn = fminf(mn, g2);
                mx = fmaxf(mx, g2);
            } else {
                float g2q = qdq_i(g2, g2_s, g2_i, g2_z);
                float u1 = qdq_i(bf2f(uv[j]), u_s, u_i, u_z);
                float o = g2q * u1;
                if (STAGEI == 2) {
                    mn = fminf(mn, o);
                    mx = fmaxf(mx, o);
                } else {
                    ov[j] = f2bf(qdq_i(o, o_s, o_i, o_z));
                }
            }
        }
        if (STAGEI == 3) *(ushort8*)(out + i) = ov;
        i += stride;
        gv = gv2;
        uv = uv2;
    }
    if (STAGEI == 1) wave_minmax_atomic(mn, mx, slots, SLOT_G2);
    if (STAGEI == 2) wave_minmax_atomic(mn, mx, slots, SLOT_O);
}
__global__ __launch_bounds__(256) void epass1(const u16* g, const u16* u, u16* o, unsigned* s) { epass_body<1>(g, u, o, s); }
__global__ __launch_bounds__(256) void epass2(const u16* g, const u16* u, u16* o, unsigned* s) { epass_body<2>(g, u, o, s); }
__global__ __launch_bounds__(256) void epass3(const u16* g, const u16* u, u16* o, unsigned* s) { epass_body<3>(g, u, o, s); }

// ---------------------------------------------------------------------------
// C = A @ B^T : A [M,K] bf16 row-major, B [N,K] bf16 row-major.
// C is bf16 (u16) or f32 per OutT. 128x128 tile, BK=64, 4 waves (2x2),
// each wave 64x64 via 4x4 mfma_16x16x32. Optionally fuses global min/max.
// Grid: 1D supertiled (SUPER_M=16, bm-inner) -> working set L3-resident.
// __launch_bounds__(256,4): 4 blocks/CU. DO NOT raise to 5: wave needs
// 60 VGPR + 64 acc = 124 unified regs > 512/5 budget -> acc spills to
// scratch (measured R7: WRITE_SIZE 89 MB -> 2.7 GB, 510 -> 1190 us).
template <bool MINMAX, typename OutT>
__device__ __forceinline__ void gemm_body(const u16* __restrict__ A, const u16* __restrict__ B,
                                          OutT* __restrict__ C, int M, int N, int K,
                                          unsigned* slots, int sidx) {
    __shared__ u16 Als[128 * 64];
    __shared__ u16 Bls[128 * 64];
    const int wave = threadIdx.x >> 6;
    const int lane = threadIdx.x & 63;
    const int wr = wave >> 1, wc = wave & 1;
    const int l15 = lane & 15, lhi = lane >> 4;

    // supertile mapping: stripes of 16 bm; within a stripe bm varies fastest
    const int ntn = N >> 7;
    const int rowspan = 16 * ntn;
    const int stripe = blockIdx.x / rowspan;
    const int rem = blockIdx.x - stripe * rowspan;
    const int bn = rem >> 4;
    const int bm = (stripe << 4) + (rem & 15);

    f32x4 acc[4][4] = {};

    const u16* Abase = A + (size_t)bm * 128 * K;
    const u16* Bbase = B + (size_t)bn * 128 * K;

    for (int k0 = 0; k0 < K; k0 += 64) {
        #pragma unroll
        for (int i = 0; i < 4; ++i) {
            int c = i * 4 + wave;            // 16 chunks of 512 elems (1KB/wave-inst)
            int e = c * 512 + lane * 8;
            int row = e >> 6, col = e & 63;
            load_lds16(Abase + (size_t)row * K + k0 + col, &Als[c * 512]);
        }
        #pragma unroll
        for (int i = 0; i < 4; ++i) {
            int c = i * 4 + wave;
            int e = c * 512 + lane * 8;
            int row = e >> 6, col = e & 63;
            load_lds16(Bbase + (size_t)row * K + k0 + col, &Bls[c * 512]);
        }
        __syncthreads();
        #pragma unroll
        for (int kk = 0; kk < 64; kk += 32) {
            bf16x8 af[4], bfr[4];
            #pragma unroll
            for (int m = 0; m < 4; ++m)
                af[m] = *(const bf16x8*)&Als[(wr * 64 + m * 16 + l15) * 64 + kk + lhi * 8];
            #pragma unroll
            for (int n = 0; n < 4; ++n)
                bfr[n] = *(const bf16x8*)&Bls[(wc * 64 + n * 16 + l15) * 64 + kk + lhi * 8];
            #pragma unroll
            for (int m = 0; m < 4; ++m)
                #pragma unroll
                for (int n = 0; n < 4; ++n)
                    acc[m][n] = __builtin_amdgcn_mfma_f32_16x16x32_bf16(af[m], bfr[n], acc[m][n], 0, 0, 0);
        }
        __syncthreads();
    }

    float mn = 0.f, mx = 0.f;
    #pragma unroll
    for (int m = 0; m < 4; ++m) {
        #pragma unroll
        for (int n = 0; n < 4; ++n) {
            int col = bn * 128 + wc * 64 + n * 16 + l15;
            int row0 = bm * 128 + wr * 64 + m * 16 + lhi * 4;
            #pragma unroll
            for (int j = 0; j < 4; ++j) {
                float f = acc[m][n][j];
                if (sizeof(OutT) == 2) {
                    u16 h = f2bf(f);
                    ((u16*)C)[(size_t)(row0 + j) * N + col] = h;
                    if (MINMAX) {
                        float g = bf2f(h);
                        mn = fminf(mn, g);
                        mx = fmaxf(mx, g);
                    }
                } else {
                    ((float*)C)[(size_t)(row0 + j) * N + col] = f;
                    if (MINMAX) {
                        mn = fminf(mn, f);
                        mx = fmaxf(mx, f);
                    }
                }
            }
        }
    }
    if (MINMAX) wave_minmax_atomic(mn, mx, slots, sidx);
}

__global__ __launch_bounds__(256, 4) void gemm_up(const u16* A, const u16* B, u16* C,
                                                  int M, int N, int K, unsigned* slots, int sidx) {
    gemm_body<true, u16>(A, B, C, M, N, K, slots, sidx);
}
__global__ __launch_bounds__(256, 4) void gemm_gate(const u16* A, const u16* B, u16* C,
                                                    int M, int N, int K, unsigned* slots, int sidx) {
    gemm_body<true, u16>(A, B, C, M, N, K, slots, sidx);
}
__global__ __launch_bounds__(256, 4) void gemm_down(const u16* A, const u16* B, float* C,
                                                    int M, int N, int K, unsigned* slots, int sidx) {
    gemm_body<false, float>(A, B, C, M, N, K, slots, sidx);
}

// ---------------------------------------------------------------------------
extern "C" void kernel_launch(void* const* d_in, const int* in_sizes, int n_in,
                              void* d_out, int out_size, void* d_ws, size_t ws_size,
                              hipStream_t stream) {
    const float* x  = (const float*)d_in[0];   // [2,2048,4096] f32
    const float* wg = (const float*)d_in[1];   // [11008,4096] f32
    const float* wu = (const float*)d_in[2];   // [11008,4096] f32
    const float* wd = (const float*)d_in[3];   // [4096,11008] f32
    float* out = (float*)d_out;                // [2,2048,4096] f32

    const int M = 4096, H = 4096, I = 11008;
    const long NX = (long)M * H;               // 16,777,216 = 2048*8192
    const long NW = (long)I * H;               // 45,088,768 = 5504*8192

    char* ws = (char*)d_ws;
    unsigned* slots = (unsigned*)ws;
    u16* xq    = (u16*)(ws + 256);
    u16* wqs   = (u16*)(ws + 256 + 33554432UL);
    u16* upb   = (u16*)(ws + 256 + 33554432UL + 90177536UL);
    u16* gateb = (u16*)(ws + 256 + 33554432UL + 2 * 90177536UL);

    init_slots<<<1, 64, 0, stream>>>(slots);
    minmax_x<<<2048, 256, 0, stream>>>(x, NX, slots, SLOT_X);
    qdq_x_kernel<<<2048, 256, 0, stream>>>(x, xq, NX, slots, SLOT_X);

    const int nwg_ug = (M / 128) * (I / 128);   // 32*86 = 2752
    const int nwg_d  = (M / 128) * (H / 128);   // 32*32 = 1024

    quant_w_up<<<5504, 256, 0, stream>>>(wu, wqs);
    gemm_up<<<nwg_ug, 256, 0, stream>>>(xq, wqs, upb, M, I, H, slots, SLOT_UP);

    quant_w_gate<<<5504, 256, 0, stream>>>(wg, wqs);
    gemm_gate<<<nwg_ug, 256, 0, stream>>>(xq, wqs, gateb, M, I, H, slots, SLOT_GATE);

    epass1<<<5504, 256, 0, stream>>>(gateb, nullptr, nullptr, slots);
    epass2<<<5504, 256, 0, stream>>>(gateb, upb, nullptr, slots);
    epass3<<<5504, 256, 0, stream>>>(gateb, upb, gateb, slots);

    quant_w_down<<<5504, 256, 0, stream>>>(wd, wqs);
    gemm_down<<<nwg_d, 256, 0, stream>>>(gateb, wqs, out, M, H, I, nullptr, 0);
}

// Round 12
// 2549.975 us; speedup vs baseline: 1.1255x; 1.1024x over previous
//
#include <hip/hip_runtime.h>
#include <hip/hip_bf16.h>

// ---------------------------------------------------------------------------
// Fully fake-quantized Llama MLP on MI355X (gfx950).
// Device inputs: float32. Device output: float32.
// Intermediates bf16; GEMMs via bf16 MFMA 16x16x32, f32 accumulate.
// R12: epass reverted to R8's grid-stride loop (grid 4096, loads in-loop).
//      R9/R10/R11's restructured epass forms were 4-5x slower (~480us each
//      vs R8's ~110) with identical math — all counters low, mechanism
//      unresolved; the empirical record decides. Div-free chain kept (R11,
//      absmax-validated). quant_w/qdq_x/minmax keep R10 single-shot
//      coalesced form (measured fast). GEMM unchanged ((256,4); (256,5)
//      spills acc -> scratch, see R7).
// ---------------------------------------------------------------------------

typedef __bf16 bf16x8 __attribute__((ext_vector_type(8)));
typedef float f32x4 __attribute__((ext_vector_type(4)));
typedef unsigned short ushort8 __attribute__((ext_vector_type(8)));
typedef unsigned short ushort4v __attribute__((ext_vector_type(4)));
typedef unsigned short u16;

#define SLOT_X 0
#define SLOT_UP 1
#define SLOT_GATE 2
#define SLOT_G2 3
#define SLOT_O 4

__device__ __forceinline__ float bf2f(u16 u) {
    return __uint_as_float(((unsigned)u) << 16);
}
__device__ __forceinline__ u16 f2bf(float f) {
    unsigned x = __float_as_uint(f);
    unsigned r = (x + 0x7FFFu + ((x >> 16) & 1u)) >> 16;  // RNE
    return (u16)r;
}

__device__ __forceinline__ unsigned encf(float f) {
    unsigned u = __float_as_uint(f);
    return (u & 0x80000000u) ? ~u : (u | 0x80000000u);
}
__device__ __forceinline__ float decf(unsigned s) {
    unsigned u = (s & 0x80000000u) ? (s ^ 0x80000000u) : ~s;
    return __uint_as_float(u);
}

__device__ __forceinline__ void wave_minmax_atomic(float mn, float mx, unsigned* slots, int sidx) {
    for (int off = 32; off; off >>= 1) {
        mn = fminf(mn, __shfl_xor(mn, off));
        mx = fmaxf(mx, __shfl_xor(mx, off));
    }
    if ((threadIdx.x & 63) == 0) {
        atomicMin(&slots[sidx * 2 + 0], encf(mn));
        atomicMax(&slots[sidx * 2 + 1], encf(mx));
    }
}

__device__ __forceinline__ void get_scale_zp(const unsigned* slots, int sidx, float& scale, float& zp) {
    float mn = decf(slots[sidx * 2 + 0]);
    float mx = decf(slots[sidx * 2 + 1]);
    scale = fmaxf((mx - mn) / 65535.0f, 1e-12f);
    zp = fminf(fmaxf(rintf(-mn / scale), 0.0f), 65535.0f);
}

// qdq with precomputed inverse scale (no per-element division)
__device__ __forceinline__ float qdq_i(float x, float scale, float inv, float zp) {
    float q = rintf(x * inv) + zp;
    q = fminf(fmaxf(q, 0.0f), 65535.0f);
    return (q - zp) * scale;
}

__device__ __forceinline__ void load_lds16(const void* g, void* l) {
    __builtin_amdgcn_global_load_lds((const __attribute__((address_space(1))) void*)g,
                                     (__attribute__((address_space(3))) void*)l, 16, 0, 0);
}

// ---------------------------------------------------------------------------
__global__ void init_slots(unsigned* slots) {
    if (threadIdx.x < 16) slots[threadIdx.x] = 0x80000000u;  // enc(0.0f)
}

// Block covers 8192 contiguous floats; lane loads 8 float4 chunks, coalesced.
__global__ __launch_bounds__(256) void minmax_x(const float* __restrict__ in, long n,
                                                unsigned* slots, int sidx) {
    long base = (long)blockIdx.x * 8192 + threadIdx.x * 4;
    float4 v[8];
    #pragma unroll
    for (int c = 0; c < 8; ++c) v[c] = *(const float4*)(in + base + c * 1024);
    float mn = 0.f, mx = 0.f;
    #pragma unroll
    for (int c = 0; c < 8; ++c) {
        mn = fminf(fminf(mn, fminf(v[c].x, v[c].y)), fminf(v[c].z, v[c].w));
        mx = fmaxf(fmaxf(mx, fmaxf(v[c].x, v[c].y)), fmaxf(v[c].z, v[c].w));
    }
    wave_minmax_atomic(mn, mx, slots, sidx);
}

// x (f32) -> qdq -> bf16. inv-scale multiplies.
__global__ __launch_bounds__(256) void qdq_x_kernel(const float* __restrict__ in, u16* __restrict__ out,
                                                    long n, const unsigned* slots, int sidx) {
    float scale, zp;
    get_scale_zp(slots, sidx, scale, zp);
    float inv = 1.0f / scale;
    long base = (long)blockIdx.x * 8192 + threadIdx.x * 4;
    float4 v[8];
    #pragma unroll
    for (int c = 0; c < 8; ++c) v[c] = *(const float4*)(in + base + c * 1024);
    #pragma unroll
    for (int c = 0; c < 8; ++c) {
        ushort4v o;
        o[0] = f2bf(qdq_i(v[c].x, scale, inv, zp));
        o[1] = f2bf(qdq_i(v[c].y, scale, inv, zp));
        o[2] = f2bf(qdq_i(v[c].z, scale, inv, zp));
        o[3] = f2bf(qdq_i(v[c].w, scale, inv, zp));
        *(ushort4v*)(out + base + c * 1024) = o;
    }
}

// per-(row, 32-block) symmetric 4-bit weight fake-quant; f32 -> bf16.
// Lane loads 8 float4 (one per 1024-float chunk) — coalesced, 8 in flight.
// Each 32-float quant block = one aligned 8-lane group: shfl_xor 1,2,4.
__device__ __forceinline__ void quant_w_body(const float* __restrict__ W, u16* __restrict__ Wq) {
    long base = (long)blockIdx.x * 8192 + threadIdx.x * 4;
    float4 v[8];
    #pragma unroll
    for (int c = 0; c < 8; ++c) v[c] = *(const float4*)(W + base + c * 1024);
    #pragma unroll
    for (int c = 0; c < 8; ++c) {
        float am = fmaxf(fmaxf(fabsf(v[c].x), fabsf(v[c].y)), fmaxf(fabsf(v[c].z), fabsf(v[c].w)));
        am = fmaxf(am, __shfl_xor(am, 1));
        am = fmaxf(am, __shfl_xor(am, 2));
        am = fmaxf(am, __shfl_xor(am, 4));
        float scale = fmaxf(am / 7.0f, 1e-12f);
        float inv = 1.0f / scale;
        ushort4v o;
        float q0 = fminf(fmaxf(rintf(v[c].x * inv), -8.0f), 7.0f);
        float q1 = fminf(fmaxf(rintf(v[c].y * inv), -8.0f), 7.0f);
        float q2 = fminf(fmaxf(rintf(v[c].z * inv), -8.0f), 7.0f);
        float q3 = fminf(fmaxf(rintf(v[c].w * inv), -8.0f), 7.0f);
        o[0] = f2bf(q0 * scale);
        o[1] = f2bf(q1 * scale);
        o[2] = f2bf(q2 * scale);
        o[3] = f2bf(q3 * scale);
        *(ushort4v*)(Wq + base + c * 1024) = o;
    }
}
__global__ __launch_bounds__(256) void quant_w_up(const float* W, u16* Wq)   { quant_w_body(W, Wq); }
__global__ __launch_bounds__(256) void quant_w_gate(const float* W, u16* Wq) { quant_w_body(W, Wq); }
__global__ __launch_bounds__(256) void quant_w_down(const float* W, u16* Wq) { quant_w_body(W, Wq); }

// elementwise chain: g1=qdq(gate); sig=fixed_qdq(sigmoid(g1)); g2=g1*sig;
// STAGE1: minmax(g2) -> SLOT_G2
// STAGE2: o = qdq(g2)*qdq(up); minmax(o) -> SLOT_O
// STAGE3: out = bf16(qdq(o))  (out aliases gate; same-index RAW per thread)
// R8-proven structure: grid-stride, runtime bound, loads inside the loop.
template <int STAGEI>
__device__ __forceinline__ void epass_body(const u16* gate, const u16* up, u16* out,
                                           long n, unsigned* slots) {
    float g_s, g_z;
    get_scale_zp(slots, SLOT_GATE, g_s, g_z);
    float g_i = 1.0f / g_s;
    float u_s = 1.f, u_z = 0.f, u_i = 1.f, g2_s = 1.f, g2_z = 0.f, g2_i = 1.f;
    float o_s = 1.f, o_z = 0.f, o_i = 1.f;
    if (STAGEI >= 2) {
        get_scale_zp(slots, SLOT_UP, u_s, u_z);   u_i = 1.0f / u_s;
        get_scale_zp(slots, SLOT_G2, g2_s, g2_z); g2_i = 1.0f / g2_s;
    }
    if (STAGEI >= 3) {
        get_scale_zp(slots, SLOT_O, o_s, o_z);    o_i = 1.0f / o_s;
    }

    long stride = (long)gridDim.x * blockDim.x * 8;
    float mn = 0.f, mx = 0.f;
    for (long i = ((long)blockIdx.x * blockDim.x + threadIdx.x) * 8; i < n; i += stride) {
        ushort8 gv = *(const ushort8*)(gate + i);
        ushort8 uv;
        if (STAGEI >= 2) uv = *(const ushort8*)(up + i);
        ushort8 ov;
        #pragma unroll
        for (int j = 0; j < 8; ++j) {
            float g1 = qdq_i(bf2f(gv[j]), g_s, g_i, g_z);
            float e = __expf(-g1);
            float s = __builtin_amdgcn_rcpf(1.0f + e);
            float sq = fminf(fmaxf(rintf(s * 65536.0f), 0.0f), 65535.0f) * (1.0f / 65536.0f);
            float g2 = g1 * sq;
            if (STAGEI == 1) {
                mn = fminf(mn, g2);
                mx = fmaxf(mx, g2);
            } else {
                float g2q = qdq_i(g2, g2_s, g2_i, g2_z);
                float u1 = qdq_i(bf2f(uv[j]), u_s, u_i, u_z);
                float o = g2q * u1;
                if (STAGEI == 2) {
                    mn = fminf(mn, o);
                    mx = fmaxf(mx, o);
                } else {
                    ov[j] = f2bf(qdq_i(o, o_s, o_i, o_z));
                }
            }
        }
        if (STAGEI == 3) *(ushort8*)(out + i) = ov;
    }
    if (STAGEI == 1) wave_minmax_atomic(mn, mx, slots, SLOT_G2);
    if (STAGEI == 2) wave_minmax_atomic(mn, mx, slots, SLOT_O);
}
__global__ __launch_bounds__(256) void epass1(const u16* g, const u16* u, u16* o, long n, unsigned* s) { epass_body<1>(g, u, o, n, s); }
__global__ __launch_bounds__(256) void epass2(const u16* g, const u16* u, u16* o, long n, unsigned* s) { epass_body<2>(g, u, o, n, s); }
__global__ __launch_bounds__(256) void epass3(const u16* g, const u16* u, u16* o, long n, unsigned* s) { epass_body<3>(g, u, o, n, s); }

// ---------------------------------------------------------------------------
// C = A @ B^T : A [M,K] bf16 row-major, B [N,K] bf16 row-major.
// C is bf16 (u16) or f32 per OutT. 128x128 tile, BK=64, 4 waves (2x2),
// each wave 64x64 via 4x4 mfma_16x16x32. Optionally fuses global min/max.
// Grid: 1D supertiled (SUPER_M=16, bm-inner) -> working set L3-resident.
// __launch_bounds__(256,4): 4 blocks/CU. DO NOT raise to 5: wave needs
// 60 VGPR + 64 acc = 124 unified regs > 512/5 budget -> acc spills to
// scratch (measured R7: WRITE_SIZE 89 MB -> 2.7 GB, 510 -> 1190 us).
template <bool MINMAX, typename OutT>
__device__ __forceinline__ void gemm_body(const u16* __restrict__ A, const u16* __restrict__ B,
                                          OutT* __restrict__ C, int M, int N, int K,
                                          unsigned* slots, int sidx) {
    __shared__ u16 Als[128 * 64];
    __shared__ u16 Bls[128 * 64];
    const int wave = threadIdx.x >> 6;
    const int lane = threadIdx.x & 63;
    const int wr = wave >> 1, wc = wave & 1;
    const int l15 = lane & 15, lhi = lane >> 4;

    // supertile mapping: stripes of 16 bm; within a stripe bm varies fastest
    const int ntn = N >> 7;
    const int rowspan = 16 * ntn;
    const int stripe = blockIdx.x / rowspan;
    const int rem = blockIdx.x - stripe * rowspan;
    const int bn = rem >> 4;
    const int bm = (stripe << 4) + (rem & 15);

    f32x4 acc[4][4] = {};

    const u16* Abase = A + (size_t)bm * 128 * K;
    const u16* Bbase = B + (size_t)bn * 128 * K;

    for (int k0 = 0; k0 < K; k0 += 64) {
        #pragma unroll
        for (int i = 0; i < 4; ++i) {
            int c = i * 4 + wave;            // 16 chunks of 512 elems (1KB/wave-inst)
            int e = c * 512 + lane * 8;
            int row = e >> 6, col = e & 63;
            load_lds16(Abase + (size_t)row * K + k0 + col, &Als[c * 512]);
        }
        #pragma unroll
        for (int i = 0; i < 4; ++i) {
            int c = i * 4 + wave;
            int e = c * 512 + lane * 8;
            int row = e >> 6, col = e & 63;
            load_lds16(Bbase + (size_t)row * K + k0 + col, &Bls[c * 512]);
        }
        __syncthreads();
        #pragma unroll
        for (int kk = 0; kk < 64; kk += 32) {
            bf16x8 af[4], bfr[4];
            #pragma unroll
            for (int m = 0; m < 4; ++m)
                af[m] = *(const bf16x8*)&Als[(wr * 64 + m * 16 + l15) * 64 + kk + lhi * 8];
            #pragma unroll
            for (int n = 0; n < 4; ++n)
                bfr[n] = *(const bf16x8*)&Bls[(wc * 64 + n * 16 + l15) * 64 + kk + lhi * 8];
            #pragma unroll
            for (int m = 0; m < 4; ++m)
                #pragma unroll
                for (int n = 0; n < 4; ++n)
                    acc[m][n] = __builtin_amdgcn_mfma_f32_16x16x32_bf16(af[m], bfr[n], acc[m][n], 0, 0, 0);
        }
        __syncthreads();
    }

    float mn = 0.f, mx = 0.f;
    #pragma unroll
    for (int m = 0; m < 4; ++m) {
        #pragma unroll
        for (int n = 0; n < 4; ++n) {
            int col = bn * 128 + wc * 64 + n * 16 + l15;
            int row0 = bm * 128 + wr * 64 + m * 16 + lhi * 4;
            #pragma unroll
            for (int j = 0; j < 4; ++j) {
                float f = acc[m][n][j];
                if (sizeof(OutT) == 2) {
                    u16 h = f2bf(f);
                    ((u16*)C)[(size_t)(row0 + j) * N + col] = h;
                    if (MINMAX) {
                        float g = bf2f(h);
                        mn = fminf(mn, g);
                        mx = fmaxf(mx, g);
                    }
                } else {
                    ((float*)C)[(size_t)(row0 + j) * N + col] = f;
                    if (MINMAX) {
                        mn = fminf(mn, f);
                        mx = fmaxf(mx, f);
                    }
                }
            }
        }
    }
    if (MINMAX) wave_minmax_atomic(mn, mx, slots, sidx);
}

__global__ __launch_bounds__(256, 4) void gemm_up(const u16* A, const u16* B, u16* C,
                                                  int M, int N, int K, unsigned* slots, int sidx) {
    gemm_body<true, u16>(A, B, C, M, N, K, slots, sidx);
}
__global__ __launch_bounds__(256, 4) void gemm_gate(const u16* A, const u16* B, u16* C,
                                                    int M, int N, int K, unsigned* slots, int sidx) {
    gemm_body<true, u16>(A, B, C, M, N, K, slots, sidx);
}
__global__ __launch_bounds__(256, 4) void gemm_down(const u16* A, const u16* B, float* C,
                                                    int M, int N, int K, unsigned* slots, int sidx) {
    gemm_body<false, float>(A, B, C, M, N, K, slots, sidx);
}

// ---------------------------------------------------------------------------
extern "C" void kernel_launch(void* const* d_in, const int* in_sizes, int n_in,
                              void* d_out, int out_size, void* d_ws, size_t ws_size,
                              hipStream_t stream) {
    const float* x  = (const float*)d_in[0];   // [2,2048,4096] f32
    const float* wg = (const float*)d_in[1];   // [11008,4096] f32
    const float* wu = (const float*)d_in[2];   // [11008,4096] f32
    const float* wd = (const float*)d_in[3];   // [4096,11008] f32
    float* out = (float*)d_out;                // [2,2048,4096] f32

    const int M = 4096, H = 4096, I = 11008;
    const long NX = (long)M * H;               // 16,777,216 = 2048*8192
    const long NW = (long)I * H;               // 45,088,768 = 5504*8192

    char* ws = (char*)d_ws;
    unsigned* slots = (unsigned*)ws;
    u16* xq    = (u16*)(ws + 256);
    u16* wqs   = (u16*)(ws + 256 + 33554432UL);
    u16* upb   = (u16*)(ws + 256 + 33554432UL + 90177536UL);
    u16* gateb = (u16*)(ws + 256 + 33554432UL + 2 * 90177536UL);

    init_slots<<<1, 64, 0, stream>>>(slots);
    minmax_x<<<2048, 256, 0, stream>>>(x, NX, slots, SLOT_X);
    qdq_x_kernel<<<2048, 256, 0, stream>>>(x, xq, NX, slots, SLOT_X);

    const int nwg_ug = (M / 128) * (I / 128);   // 32*86 = 2752
    const int nwg_d  = (M / 128) * (H / 128);   // 32*32 = 1024

    quant_w_up<<<5504, 256, 0, stream>>>(wu, wqs);
    gemm_up<<<nwg_ug, 256, 0, stream>>>(xq, wqs, upb, M, I, H, slots, SLOT_UP);

    quant_w_gate<<<5504, 256, 0, stream>>>(wg, wqs);
    gemm_gate<<<nwg_ug, 256, 0, stream>>>(xq, wqs, gateb, M, I, H, slots, SLOT_GATE);

    epass1<<<4096, 256, 0, stream>>>(gateb, nullptr, nullptr, NW, slots);
    epass2<<<4096, 256, 0, stream>>>(gateb, upb, nullptr, NW, slots);
    epass3<<<4096, 256, 0, stream>>>(gateb, upb, gateb, NW, slots);

    quant_w_down<<<5504, 256, 0, stream>>>(wd, wqs);
    gemm_down<<<nwg_d, 256, 0, stream>>>(gateb, wqs, out, M, H, I, nullptr, 0);
}

// Round 13
// 1671.558 us; speedup vs baseline: 1.7170x; 1.5255x over previous
//
#include <hip/hip_runtime.h>
#include <hip/hip_bf16.h>

// ---------------------------------------------------------------------------
// Fully fake-quantized Llama MLP on MI355X (gfx950).
// Device inputs: float32. Device output: float32.
// Intermediates bf16; GEMMs via bf16 MFMA 16x16x32, f32 accumulate.
// R13: atomic-storm fix (Guideline 12). Block-level LDS min/max reduction
//      (one atomic pair per block, was per wave) + per-XCD slot sharding x8
//      (atomics spread over 8 cache lines; readers reduce 8 copies).
//      Hypothesis from R10 counters: epass2 517us with VALUBusy 18%,
//      HBM 177 GB/s, nothing issuing 82% of time -> serialized same-address
//      device-scope atomics (32k RMWs through one L2 bank).
//      Everything else unchanged from R12.
// ---------------------------------------------------------------------------

typedef __bf16 bf16x8 __attribute__((ext_vector_type(8)));
typedef float f32x4 __attribute__((ext_vector_type(4)));
typedef unsigned short ushort8 __attribute__((ext_vector_type(8)));
typedef unsigned short ushort4v __attribute__((ext_vector_type(4)));
typedef unsigned short u16;

#define SLOT_X 0
#define SLOT_UP 1
#define SLOT_GATE 2
#define SLOT_G2 3
#define SLOT_O 4
// slot layout: [(slot*8 + copy)*2 + {0=min,1=max}], copy = blockIdx & 7

__device__ __forceinline__ float bf2f(u16 u) {
    return __uint_as_float(((unsigned)u) << 16);
}
__device__ __forceinline__ u16 f2bf(float f) {
    unsigned x = __float_as_uint(f);
    unsigned r = (x + 0x7FFFu + ((x >> 16) & 1u)) >> 16;  // RNE
    return (u16)r;
}

__device__ __forceinline__ unsigned encf(float f) {
    unsigned u = __float_as_uint(f);
    return (u & 0x80000000u) ? ~u : (u | 0x80000000u);
}
__device__ __forceinline__ float decf(unsigned s) {
    unsigned u = (s & 0x80000000u) ? (s ^ 0x80000000u) : ~s;
    return __uint_as_float(u);
}

// block-level min/max reduction -> ONE atomic pair per block, sharded by XCD
__device__ __forceinline__ void block_minmax_atomic(float mn, float mx, unsigned* slots, int sidx) {
    #pragma unroll
    for (int off = 32; off; off >>= 1) {
        mn = fminf(mn, __shfl_xor(mn, off));
        mx = fmaxf(mx, __shfl_xor(mx, off));
    }
    __shared__ float red[8];
    int w = threadIdx.x >> 6;
    if ((threadIdx.x & 63) == 0) { red[w * 2] = mn; red[w * 2 + 1] = mx; }
    __syncthreads();
    if (threadIdx.x == 0) {
        float m0 = red[0], m1 = red[1];
        #pragma unroll
        for (int i = 1; i < 4; ++i) {
            m0 = fminf(m0, red[i * 2]);
            m1 = fmaxf(m1, red[i * 2 + 1]);
        }
        int c = blockIdx.x & 7;
        atomicMin(&slots[(sidx * 8 + c) * 2 + 0], encf(m0));
        atomicMax(&slots[(sidx * 8 + c) * 2 + 1], encf(m1));
    }
}

__device__ __forceinline__ void get_scale_zp(const unsigned* slots, int sidx, float& scale, float& zp) {
    unsigned emn = 0xFFFFFFFFu, emx = 0u;
    #pragma unroll
    for (int c = 0; c < 8; ++c) {
        unsigned a = slots[(sidx * 8 + c) * 2 + 0];
        unsigned b = slots[(sidx * 8 + c) * 2 + 1];
        emn = (a < emn) ? a : emn;
        emx = (b > emx) ? b : emx;
    }
    float mn = decf(emn), mx = decf(emx);
    scale = fmaxf((mx - mn) / 65535.0f, 1e-12f);
    zp = fminf(fmaxf(rintf(-mn / scale), 0.0f), 65535.0f);
}

// qdq with precomputed inverse scale (no per-element division)
__device__ __forceinline__ float qdq_i(float x, float scale, float inv, float zp) {
    float q = rintf(x * inv) + zp;
    q = fminf(fmaxf(q, 0.0f), 65535.0f);
    return (q - zp) * scale;
}

__device__ __forceinline__ void load_lds16(const void* g, void* l) {
    __builtin_amdgcn_global_load_lds((const __attribute__((address_space(1))) void*)g,
                                     (__attribute__((address_space(3))) void*)l, 16, 0, 0);
}

// ---------------------------------------------------------------------------
__global__ void init_slots(unsigned* slots) {
    if (threadIdx.x < 128) slots[threadIdx.x] = 0x80000000u;  // enc(0.0f)
}

// Block covers 8192 contiguous floats; lane loads 8 float4 chunks, coalesced.
__global__ __launch_bounds__(256) void minmax_x(const float* __restrict__ in, long n,
                                                unsigned* slots, int sidx) {
    long base = (long)blockIdx.x * 8192 + threadIdx.x * 4;
    float4 v[8];
    #pragma unroll
    for (int c = 0; c < 8; ++c) v[c] = *(const float4*)(in + base + c * 1024);
    float mn = 0.f, mx = 0.f;
    #pragma unroll
    for (int c = 0; c < 8; ++c) {
        mn = fminf(fminf(mn, fminf(v[c].x, v[c].y)), fminf(v[c].z, v[c].w));
        mx = fmaxf(fmaxf(mx, fmaxf(v[c].x, v[c].y)), fmaxf(v[c].z, v[c].w));
    }
    block_minmax_atomic(mn, mx, slots, sidx);
}

// x (f32) -> qdq -> bf16. inv-scale multiplies.
__global__ __launch_bounds__(256) void qdq_x_kernel(const float* __restrict__ in, u16* __restrict__ out,
                                                    long n, const unsigned* slots, int sidx) {
    float scale, zp;
    get_scale_zp(slots, sidx, scale, zp);
    float inv = 1.0f / scale;
    long base = (long)blockIdx.x * 8192 + threadIdx.x * 4;
    float4 v[8];
    #pragma unroll
    for (int c = 0; c < 8; ++c) v[c] = *(const float4*)(in + base + c * 1024);
    #pragma unroll
    for (int c = 0; c < 8; ++c) {
        ushort4v o;
        o[0] = f2bf(qdq_i(v[c].x, scale, inv, zp));
        o[1] = f2bf(qdq_i(v[c].y, scale, inv, zp));
        o[2] = f2bf(qdq_i(v[c].z, scale, inv, zp));
        o[3] = f2bf(qdq_i(v[c].w, scale, inv, zp));
        *(ushort4v*)(out + base + c * 1024) = o;
    }
}

// per-(row, 32-block) symmetric 4-bit weight fake-quant; f32 -> bf16.
// Lane loads 8 float4 (one per 1024-float chunk) — coalesced, 8 in flight.
// Each 32-float quant block = one aligned 8-lane group: shfl_xor 1,2,4.
__device__ __forceinline__ void quant_w_body(const float* __restrict__ W, u16* __restrict__ Wq) {
    long base = (long)blockIdx.x * 8192 + threadIdx.x * 4;
    float4 v[8];
    #pragma unroll
    for (int c = 0; c < 8; ++c) v[c] = *(const float4*)(W + base + c * 1024);
    #pragma unroll
    for (int c = 0; c < 8; ++c) {
        float am = fmaxf(fmaxf(fabsf(v[c].x), fabsf(v[c].y)), fmaxf(fabsf(v[c].z), fabsf(v[c].w)));
        am = fmaxf(am, __shfl_xor(am, 1));
        am = fmaxf(am, __shfl_xor(am, 2));
        am = fmaxf(am, __shfl_xor(am, 4));
        float scale = fmaxf(am / 7.0f, 1e-12f);
        float inv = 1.0f / scale;
        ushort4v o;
        float q0 = fminf(fmaxf(rintf(v[c].x * inv), -8.0f), 7.0f);
        float q1 = fminf(fmaxf(rintf(v[c].y * inv), -8.0f), 7.0f);
        float q2 = fminf(fmaxf(rintf(v[c].z * inv), -8.0f), 7.0f);
        float q3 = fminf(fmaxf(rintf(v[c].w * inv), -8.0f), 7.0f);
        o[0] = f2bf(q0 * scale);
        o[1] = f2bf(q1 * scale);
        o[2] = f2bf(q2 * scale);
        o[3] = f2bf(q3 * scale);
        *(ushort4v*)(Wq + base + c * 1024) = o;
    }
}
__global__ __launch_bounds__(256) void quant_w_up(const float* W, u16* Wq)   { quant_w_body(W, Wq); }
__global__ __launch_bounds__(256) void quant_w_gate(const float* W, u16* Wq) { quant_w_body(W, Wq); }
__global__ __launch_bounds__(256) void quant_w_down(const float* W, u16* Wq) { quant_w_body(W, Wq); }

// elementwise chain: g1=qdq(gate); sig=fixed_qdq(sigmoid(g1)); g2=g1*sig;
// STAGE1: minmax(g2) -> SLOT_G2
// STAGE2: o = qdq(g2)*qdq(up); minmax(o) -> SLOT_O
// STAGE3: out = bf16(qdq(o))  (out aliases gate; same-index RAW per thread)
// R8-proven structure: grid-stride, runtime bound, loads inside the loop.
template <int STAGEI>
__device__ __forceinline__ void epass_body(const u16* gate, const u16* up, u16* out,
                                           long n, unsigned* slots) {
    float g_s, g_z;
    get_scale_zp(slots, SLOT_GATE, g_s, g_z);
    float g_i = 1.0f / g_s;
    float u_s = 1.f, u_z = 0.f, u_i = 1.f, g2_s = 1.f, g2_z = 0.f, g2_i = 1.f;
    float o_s = 1.f, o_z = 0.f, o_i = 1.f;
    if (STAGEI >= 2) {
        get_scale_zp(slots, SLOT_UP, u_s, u_z);   u_i = 1.0f / u_s;
        get_scale_zp(slots, SLOT_G2, g2_s, g2_z); g2_i = 1.0f / g2_s;
    }
    if (STAGEI >= 3) {
        get_scale_zp(slots, SLOT_O, o_s, o_z);    o_i = 1.0f / o_s;
    }

    long stride = (long)gridDim.x * blockDim.x * 8;
    float mn = 0.f, mx = 0.f;
    for (long i = ((long)blockIdx.x * blockDim.x + threadIdx.x) * 8; i < n; i += stride) {
        ushort8 gv = *(const ushort8*)(gate + i);
        ushort8 uv;
        if (STAGEI >= 2) uv = *(const ushort8*)(up + i);
        ushort8 ov;
        #pragma unroll
        for (int j = 0; j < 8; ++j) {
            float g1 = qdq_i(bf2f(gv[j]), g_s, g_i, g_z);
            float e = __expf(-g1);
            float s = __builtin_amdgcn_rcpf(1.0f + e);
            float sq = fminf(fmaxf(rintf(s * 65536.0f), 0.0f), 65535.0f) * (1.0f / 65536.0f);
            float g2 = g1 * sq;
            if (STAGEI == 1) {
                mn = fminf(mn, g2);
                mx = fmaxf(mx, g2);
            } else {
                float g2q = qdq_i(g2, g2_s, g2_i, g2_z);
                float u1 = qdq_i(bf2f(uv[j]), u_s, u_i, u_z);
                float o = g2q * u1;
                if (STAGEI == 2) {
                    mn = fminf(mn, o);
                    mx = fmaxf(mx, o);
                } else {
                    ov[j] = f2bf(qdq_i(o, o_s, o_i, o_z));
                }
            }
        }
        if (STAGEI == 3) *(ushort8*)(out + i) = ov;
    }
    if (STAGEI == 1) block_minmax_atomic(mn, mx, slots, SLOT_G2);
    if (STAGEI == 2) block_minmax_atomic(mn, mx, slots, SLOT_O);
}
__global__ __launch_bounds__(256) void epass1(const u16* g, const u16* u, u16* o, long n, unsigned* s) { epass_body<1>(g, u, o, n, s); }
__global__ __launch_bounds__(256) void epass2(const u16* g, const u16* u, u16* o, long n, unsigned* s) { epass_body<2>(g, u, o, n, s); }
__global__ __launch_bounds__(256) void epass3(const u16* g, const u16* u, u16* o, long n, unsigned* s) { epass_body<3>(g, u, o, n, s); }

// ---------------------------------------------------------------------------
// C = A @ B^T : A [M,K] bf16 row-major, B [N,K] bf16 row-major.
// C is bf16 (u16) or f32 per OutT. 128x128 tile, BK=64, 4 waves (2x2),
// each wave 64x64 via 4x4 mfma_16x16x32. Optionally fuses global min/max.
// Grid: 1D supertiled (SUPER_M=16, bm-inner) -> working set L3-resident.
// __launch_bounds__(256,4): 4 blocks/CU. DO NOT raise to 5: wave needs
// 60 VGPR + 64 acc = 124 unified regs > 512/5 budget -> acc spills to
// scratch (measured R7: WRITE_SIZE 89 MB -> 2.7 GB, 510 -> 1190 us).
template <bool MINMAX, typename OutT>
__device__ __forceinline__ void gemm_body(const u16* __restrict__ A, const u16* __restrict__ B,
                                          OutT* __restrict__ C, int M, int N, int K,
                                          unsigned* slots, int sidx) {
    __shared__ u16 Als[128 * 64];
    __shared__ u16 Bls[128 * 64];
    const int wave = threadIdx.x >> 6;
    const int lane = threadIdx.x & 63;
    const int wr = wave >> 1, wc = wave & 1;
    const int l15 = lane & 15, lhi = lane >> 4;

    // supertile mapping: stripes of 16 bm; within a stripe bm varies fastest
    const int ntn = N >> 7;
    const int rowspan = 16 * ntn;
    const int stripe = blockIdx.x / rowspan;
    const int rem = blockIdx.x - stripe * rowspan;
    const int bn = rem >> 4;
    const int bm = (stripe << 4) + (rem & 15);

    f32x4 acc[4][4] = {};

    const u16* Abase = A + (size_t)bm * 128 * K;
    const u16* Bbase = B + (size_t)bn * 128 * K;

    for (int k0 = 0; k0 < K; k0 += 64) {
        #pragma unroll
        for (int i = 0; i < 4; ++i) {
            int c = i * 4 + wave;            // 16 chunks of 512 elems (1KB/wave-inst)
            int e = c * 512 + lane * 8;
            int row = e >> 6, col = e & 63;
            load_lds16(Abase + (size_t)row * K + k0 + col, &Als[c * 512]);
        }
        #pragma unroll
        for (int i = 0; i < 4; ++i) {
            int c = i * 4 + wave;
            int e = c * 512 + lane * 8;
            int row = e >> 6, col = e & 63;
            load_lds16(Bbase + (size_t)row * K + k0 + col, &Bls[c * 512]);
        }
        __syncthreads();
        #pragma unroll
        for (int kk = 0; kk < 64; kk += 32) {
            bf16x8 af[4], bfr[4];
            #pragma unroll
            for (int m = 0; m < 4; ++m)
                af[m] = *(const bf16x8*)&Als[(wr * 64 + m * 16 + l15) * 64 + kk + lhi * 8];
            #pragma unroll
            for (int n = 0; n < 4; ++n)
                bfr[n] = *(const bf16x8*)&Bls[(wc * 64 + n * 16 + l15) * 64 + kk + lhi * 8];
            #pragma unroll
            for (int m = 0; m < 4; ++m)
                #pragma unroll
                for (int n = 0; n < 4; ++n)
                    acc[m][n] = __builtin_amdgcn_mfma_f32_16x16x32_bf16(af[m], bfr[n], acc[m][n], 0, 0, 0);
        }
        __syncthreads();
    }

    float mn = 0.f, mx = 0.f;
    #pragma unroll
    for (int m = 0; m < 4; ++m) {
        #pragma unroll
        for (int n = 0; n < 4; ++n) {
            int col = bn * 128 + wc * 64 + n * 16 + l15;
            int row0 = bm * 128 + wr * 64 + m * 16 + lhi * 4;
            #pragma unroll
            for (int j = 0; j < 4; ++j) {
                float f = acc[m][n][j];
                if (sizeof(OutT) == 2) {
                    u16 h = f2bf(f);
                    ((u16*)C)[(size_t)(row0 + j) * N + col] = h;
                    if (MINMAX) {
                        float g = bf2f(h);
                        mn = fminf(mn, g);
                        mx = fmaxf(mx, g);
                    }
                } else {
                    ((float*)C)[(size_t)(row0 + j) * N + col] = f;
                    if (MINMAX) {
                        mn = fminf(mn, f);
                        mx = fmaxf(mx, f);
                    }
                }
            }
        }
    }
    if (MINMAX) block_minmax_atomic(mn, mx, slots, sidx);
}

__global__ __launch_bounds__(256, 4) void gemm_up(const u16* A, const u16* B, u16* C,
                                                  int M, int N, int K, unsigned* slots, int sidx) {
    gemm_body<true, u16>(A, B, C, M, N, K, slots, sidx);
}
__global__ __launch_bounds__(256, 4) void gemm_gate(const u16* A, const u16* B, u16* C,
                                                    int M, int N, int K, unsigned* slots, int sidx) {
    gemm_body<true, u16>(A, B, C, M, N, K, slots, sidx);
}
__global__ __launch_bounds__(256, 4) void gemm_down(const u16* A, const u16* B, float* C,
                                                    int M, int N, int K, unsigned* slots, int sidx) {
    gemm_body<false, float>(A, B, C, M, N, K, slots, sidx);
}

// ---------------------------------------------------------------------------
extern "C" void kernel_launch(void* const* d_in, const int* in_sizes, int n_in,
                              void* d_out, int out_size, void* d_ws, size_t ws_size,
                              hipStream_t stream) {
    const float* x  = (const float*)d_in[0];   // [2,2048,4096] f32
    const float* wg = (const float*)d_in[1];   // [11008,4096] f32
    const float* wu = (const float*)d_in[2];   // [11008,4096] f32
    const float* wd = (const float*)d_in[3];   // [4096,11008] f32
    float* out = (float*)d_out;                // [2,2048,4096] f32

    const int M = 4096, H = 4096, I = 11008;
    const long NX = (long)M * H;               // 16,777,216 = 2048*8192
    const long NW = (long)I * H;               // 45,088,768 = 5504*8192

    char* ws = (char*)d_ws;
    unsigned* slots = (unsigned*)ws;           // 128 entries (5 slots x 8 copies x 2)
    u16* xq    = (u16*)(ws + 1024);
    u16* wqs   = (u16*)(ws + 1024 + 33554432UL);
    u16* upb   = (u16*)(ws + 1024 + 33554432UL + 90177536UL);
    u16* gateb = (u16*)(ws + 1024 + 33554432UL + 2 * 90177536UL);

    init_slots<<<1, 128, 0, stream>>>(slots);
    minmax_x<<<2048, 256, 0, stream>>>(x, NX, slots, SLOT_X);
    qdq_x_kernel<<<2048, 256, 0, stream>>>(x, xq, NX, slots, SLOT_X);

    const int nwg_ug = (M / 128) * (I / 128);   // 32*86 = 2752
    const int nwg_d  = (M / 128) * (H / 128);   // 32*32 = 1024

    quant_w_up<<<5504, 256, 0, stream>>>(wu, wqs);
    gemm_up<<<nwg_ug, 256, 0, stream>>>(xq, wqs, upb, M, I, H, slots, SLOT_UP);

    quant_w_gate<<<5504, 256, 0, stream>>>(wg, wqs);
    gemm_gate<<<nwg_ug, 256, 0, stream>>>(xq, wqs, gateb, M, I, H, slots, SLOT_GATE);

    epass1<<<4096, 256, 0, stream>>>(gateb, nullptr, nullptr, NW, slots);
    epass2<<<4096, 256, 0, stream>>>(gateb, upb, nullptr, NW, slots);
    epass3<<<4096, 256, 0, stream>>>(gateb, upb, gateb, NW, slots);

    quant_w_down<<<5504, 256, 0, stream>>>(wd, wqs);
    gemm_down<<<nwg_d, 256, 0, stream>>>(gateb, wqs, out, M, H, I, nullptr, 0);
}